// Round 1
// baseline (499.344 us; speedup 1.0000x reference)
//
#include <hip/hip_runtime.h>
#include <stdint.h>

#define BATCH 4
#define A_NUM 2
#define LOCS 262144                 // HT / B
#define HT (BATCH * LOCS)           // 1048576
#define NPB (LOCS * A_NUM)          // 524288 candidates per batch
#define TOTAL (A_NUM * HT)          // 2097152 objectness elements
#define PRE_NMS 2048
#define POST_NMS 512
#define NMS_THRESH_F 0.7f
#define NBUCKET 4096
#define CAND_CAP 8192
#define PAIR_CAP 4096

// workspace byte offsets
#define OFF_HIST 0                  // 4 * 4096 * 4   = 65536
#define OFF_CTRL 65536              // 512 bytes: [0..3]=candCount [4..7]=T [8..11]=countAbove [12..15]=pairCount
#define OFF_CAND 66048              // 4 * 8192 * 8   = 262144
#define OFF_BOXES 328192            // 4 * 2048 * 7*4 = 229376
#define OFF_SCORE 557568            // 4 * 2048 * 4   = 32768
#define OFF_PAIRS 590336            // 4 * 4096 * 8   = 131072
// total ws use: 721408 bytes

__device__ __forceinline__ uint32_t f2key(float f) {
    uint32_t u = __float_as_uint(f);
    return (u & 0x80000000u) ? ~u : (u | 0x80000000u);  // monotone ascending
}

// ---------------- K1: per-batch histogram over top-12 key bits ----------------
__global__ void k_hist(const float* __restrict__ obj, uint32_t* __restrict__ hist) {
    __shared__ uint32_t h[NBUCKET];
    for (int j = threadIdx.x; j < NBUCKET; j += 256) h[j] = 0;
    __syncthreads();
    int base = blockIdx.x * 4096;                 // 4096-aligned => one (a,b) chunk
    int b = (base % HT) / LOCS;
    for (int k = 0; k < 16; ++k) {
        int g = base + k * 256 + threadIdx.x;
        uint32_t key = f2key(obj[g]);
        atomicAdd(&h[key >> 20], 1u);
    }
    __syncthreads();
    uint32_t* gh = hist + b * NBUCKET;
    for (int j = threadIdx.x; j < NBUCKET; j += 256)
        if (h[j]) atomicAdd(&gh[j], h[j]);
}

// ---------------- K2: find threshold bucket T and countAbove ----------------
__global__ void k_thresh(const uint32_t* __restrict__ hist, uint32_t* __restrict__ ctrl) {
    int b = blockIdx.x;
    const uint32_t* gh = hist + b * NBUCKET;
    __shared__ uint32_t s[64], sa[64];
    int l = threadIdx.x;                          // 64 threads
    uint32_t sum = 0;
    for (int j = 0; j < 64; ++j) sum += gh[l * 64 + j];
    s[l] = sum;
    __syncthreads();
    if (l == 0) {
        uint32_t acc = 0;
        for (int m = 63; m >= 0; --m) { sa[m] = acc; acc += s[m]; }
    }
    __syncthreads();
    if (sa[l] < PRE_NMS && sa[l] + s[l] >= PRE_NMS) {   // unique lane
        uint32_t cum = sa[l];
        for (int j = 63; j >= 0; --j) {
            uint32_t hv = gh[l * 64 + j];
            if (cum + hv >= PRE_NMS) { ctrl[4 + b] = (uint32_t)(l * 64 + j); ctrl[8 + b] = cum; break; }
            cum += hv;
        }
    }
}

// ---------------- K3: compact candidates with bucket >= T ----------------
__global__ void k_compact(const float* __restrict__ obj, uint32_t* __restrict__ ctrl,
                          unsigned long long* __restrict__ cand) {
    int base = blockIdx.x * 4096;
    int b = (base % HT) / LOCS;
    int a = base / HT;
    uint32_t T = ctrl[4 + b];
    for (int k = 0; k < 16; ++k) {
        int g = base + k * 256 + threadIdx.x;
        uint32_t key = f2key(obj[g]);
        if ((key >> 20) >= T) {
            int loc = g & (LOCS - 1);             // LOCS is pow2
            uint32_t i = (uint32_t)(loc * A_NUM + a);
            uint32_t pos = atomicAdd(&ctrl[b], 1u);
            if (pos < CAND_CAP)
                cand[(size_t)b * CAND_CAP + pos] =
                    ((unsigned long long)key << 32) | (uint32_t)(~i);
        }
    }
}

// ---------------- K4: per-batch bitonic sort (descending) + decode top-2048 ----------------
__global__ __launch_bounds__(1024) void k_sort_decode(
    const float* __restrict__ breg, const float* __restrict__ anchors,
    const uint32_t* __restrict__ ctrl, const unsigned long long* __restrict__ cand,
    float* __restrict__ boxes, float* __restrict__ scores) {
    __shared__ unsigned long long e[CAND_CAP];
    int b = blockIdx.x;
    uint32_t n = ctrl[b];
    if (n > CAND_CAP) n = CAND_CAP;
    unsigned np2 = 2048;
    while (np2 < n) np2 <<= 1;
    const unsigned long long* cb = cand + (size_t)b * CAND_CAP;
    for (unsigned j = threadIdx.x; j < np2; j += 1024) e[j] = (j < n) ? cb[j] : 0ull;
    __syncthreads();
    for (unsigned size = 2; size <= np2; size <<= 1)
        for (unsigned stride = size >> 1; stride > 0; stride >>= 1) {
            for (unsigned q = threadIdx.x; q < (np2 >> 1); q += 1024) {
                unsigned p = 2 * q - (q & (stride - 1));
                unsigned partner = p + stride;
                bool up = ((p & size) == 0);
                unsigned long long x = e[p], y = e[partner];
                if (up ? (x < y) : (x > y)) { e[p] = y; e[partner] = x; }  // descending
            }
            __syncthreads();
        }
    // decode top PRE_NMS
    for (unsigned j = threadIdx.x; j < PRE_NMS; j += 1024) {
        unsigned long long p = e[j];
        uint32_t key = (uint32_t)(p >> 32);
        uint32_t i = ~(uint32_t)p;
        uint32_t u = (key & 0x80000000u) ? (key ^ 0x80000000u) : ~key;
        float v = __uint_as_float(u);
        scores[b * PRE_NMS + j] = 1.0f / (1.0f + expf(-v));
        int a = (int)(i & 1);
        int loc = (int)(i >> 1);
        int t = b * LOCS + loc;
        float d[7];
        #pragma unroll
        for (int c = 0; c < 7; ++c) d[c] = breg[(size_t)(a * 7 + c) * HT + t];
        const float* anc = anchors + ((size_t)b * NPB + i) * 7;
        float xa = anc[0], ya = anc[1], za = anc[2];
        float wa = anc[3], la = anc[4], ha = anc[5], ra = anc[6];
        float diag = sqrtf(wa * wa + la * la);
        float* bx = boxes + ((size_t)b * PRE_NMS + j) * 7;
        bx[0] = d[0] * diag + xa;
        bx[1] = d[1] * diag + ya;
        bx[2] = d[2] * ha + za;
        bx[3] = expf(d[3]) * wa;
        bx[4] = expf(d[4]) * la;
        bx[5] = expf(d[5]) * ha;
        bx[6] = d[6] + ra;
    }
}

// ---------------- K5: find suppressing pairs (iou > thresh, j > i) ----------------
__global__ __launch_bounds__(1024) void k_pairs(const float* __restrict__ boxes,
                                                uint32_t* __restrict__ pairCount,
                                                unsigned long long* __restrict__ pairs) {
    int b = blockIdx.x >> 1;
    int half = blockIdx.x & 1;
    __shared__ float x1[PRE_NMS], x2[PRE_NMS], y1[PRE_NMS], y2[PRE_NMS];
    __shared__ float z1[PRE_NMS], z2[PRE_NMS], vol[PRE_NMS];
    for (int j = threadIdx.x; j < PRE_NMS; j += 1024) {
        const float* bx = boxes + ((size_t)b * PRE_NMS + j) * 7;
        float x = bx[0], y = bx[1], z = bx[2], w = bx[3], l = bx[4], h = bx[5];
        x1[j] = x - 0.5f * w; x2[j] = x + 0.5f * w;
        y1[j] = y - 0.5f * l; y2[j] = y + 0.5f * l;
        z1[j] = z;            z2[j] = z + h;
        vol[j] = fmaxf(w, 0.f) * fmaxf(l, 0.f) * fmaxf(h, 0.f);
    }
    __syncthreads();
    int i = half * 1024 + threadIdx.x;
    float xi1 = x1[i], xi2 = x2[i], yi1 = y1[i], yi2 = y2[i];
    float zi1 = z1[i], zi2 = z2[i], vi = vol[i];
    for (int j = i + 1; j < PRE_NMS; ++j) {
        float ix = fminf(xi2, x2[j]) - fmaxf(xi1, x1[j]); if (ix <= 0.f) continue;
        float iy = fminf(yi2, y2[j]) - fmaxf(yi1, y1[j]); if (iy <= 0.f) continue;
        float iz = fminf(zi2, z2[j]) - fmaxf(zi1, z1[j]); if (iz <= 0.f) continue;
        float inter = ix * iy * iz;
        float iou = inter / (vi + vol[j] - inter + 1e-8f);
        if (iou > NMS_THRESH_F) {
            uint32_t pos = atomicAdd(pairCount, 0u) , dummy = 0; (void)dummy;
            pos = atomicAdd(&pairCount[b], 1u);
            if (pos < PAIR_CAP)
                pairs[(size_t)b * PAIR_CAP + pos] = ((unsigned long long)(uint32_t)i << 32) | (uint32_t)j;
        }
    }
}

// ---------------- K6: serial greedy scan over tiny pair list + emit output ----------------
__global__ __launch_bounds__(256) void k_scan_out(const float* __restrict__ boxes,
                                                  const float* __restrict__ scores,
                                                  const uint32_t* __restrict__ ctrl,
                                                  const unsigned long long* __restrict__ pairs,
                                                  float* __restrict__ out) {
    int b = blockIdx.x;
    __shared__ unsigned long long pl[PAIR_CAP];
    __shared__ unsigned long long keep[32];
    __shared__ uint32_t keptPre[33];
    uint32_t np = ctrl[12 + b];
    if (np > PAIR_CAP) np = PAIR_CAP;
    unsigned np2 = 64;
    while (np2 < np) np2 <<= 1;
    for (unsigned j = threadIdx.x; j < np2; j += 256)
        pl[j] = (j < np) ? pairs[(size_t)b * PAIR_CAP + j] : ~0ull;
    __syncthreads();
    for (unsigned size = 2; size <= np2; size <<= 1)
        for (unsigned stride = size >> 1; stride > 0; stride >>= 1) {
            for (unsigned q = threadIdx.x; q < (np2 >> 1); q += 256) {
                unsigned p = 2 * q - (q & (stride - 1));
                unsigned partner = p + stride;
                bool up = ((p & size) == 0);
                unsigned long long x = pl[p], y = pl[partner];
                if (up ? (x > y) : (x < y)) { pl[p] = y; pl[partner] = x; }  // ascending
            }
            __syncthreads();
        }
    if (threadIdx.x == 0) {
        for (int w = 0; w < 32; ++w) keep[w] = ~0ull;
        for (unsigned p = 0; p < np; ++p) {
            unsigned long long e = pl[p];
            uint32_t i = (uint32_t)(e >> 32), j = (uint32_t)e;
            if ((keep[i >> 6] >> (i & 63)) & 1ull)
                keep[j >> 6] &= ~(1ull << (j & 63));
        }
        uint32_t acc = 0;
        for (int w = 0; w < 32; ++w) { keptPre[w] = acc; acc += (uint32_t)__popcll(keep[w]); }
        keptPre[32] = acc;
    }
    __syncthreads();
    uint32_t totalKept = keptPre[32];
    for (int i = threadIdx.x; i < PRE_NMS; i += 256) {
        int w = i >> 6, bit = i & 63;
        unsigned long long kw = keep[w];
        uint32_t keptBefore = keptPre[w] + (uint32_t)__popcll(kw & ((1ull << bit) - 1ull));
        bool isKept = (kw >> bit) & 1ull;
        uint32_t pos = isKept ? keptBefore : (totalKept + (uint32_t)i - keptBefore);
        if (pos < POST_NMS) {
            float* o = out + ((size_t)b * POST_NMS + pos) * 8;
            const float* bx = boxes + ((size_t)b * PRE_NMS + i) * 7;
            #pragma unroll
            for (int c = 0; c < 7; ++c) o[c] = bx[c];
            o[7] = isKept ? scores[b * PRE_NMS + i] : 0.0f;
        }
    }
}

extern "C" void kernel_launch(void* const* d_in, const int* in_sizes, int n_in,
                              void* d_out, int out_size, void* d_ws, size_t ws_size,
                              hipStream_t stream) {
    const float* obj = (const float*)d_in[0];
    const float* breg = (const float*)d_in[1];
    const float* anchors = (const float*)d_in[2];
    float* out = (float*)d_out;
    char* ws = (char*)d_ws;
    uint32_t* hist = (uint32_t*)(ws + OFF_HIST);
    uint32_t* ctrl = (uint32_t*)(ws + OFF_CTRL);
    unsigned long long* cand = (unsigned long long*)(ws + OFF_CAND);
    float* boxes = (float*)(ws + OFF_BOXES);
    float* scores = (float*)(ws + OFF_SCORE);
    unsigned long long* pairs = (unsigned long long*)(ws + OFF_PAIRS);

    hipMemsetAsync(d_ws, 0, OFF_CAND, stream);  // zero hist + ctrl each call

    k_hist<<<TOTAL / 4096, 256, 0, stream>>>(obj, hist);
    k_thresh<<<BATCH, 64, 0, stream>>>(hist, ctrl);
    k_compact<<<TOTAL / 4096, 256, 0, stream>>>(obj, ctrl, cand);
    k_sort_decode<<<BATCH, 1024, 0, stream>>>(breg, anchors, ctrl, cand, boxes, scores);
    k_pairs<<<BATCH * 2, 1024, 0, stream>>>(boxes, ctrl + 12, pairs);
    k_scan_out<<<BATCH, 256, 0, stream>>>(boxes, scores, ctrl, pairs, out);
}

// Round 2
// 301.078 us; speedup vs baseline: 1.6585x; 1.6585x over previous
//
#include <hip/hip_runtime.h>
#include <stdint.h>

#define BATCH 4
#define A_NUM 2
#define LOCS 262144                 // HT / B
#define HT (BATCH * LOCS)           // 1048576
#define NPB (LOCS * A_NUM)          // 524288 candidates per batch
#define TOTAL (A_NUM * HT)          // 2097152 objectness elements
#define PRE_NMS 2048
#define POST_NMS 512
#define NMS_THRESH_F 0.7f
#define NBUCKET 4096
#define CAND_CAP 8192
#define PAIR_CAP 4096
#define ITILE 64

// workspace byte offsets
#define OFF_HIST 0                  // 4 * 4096 * 4   = 65536
#define OFF_CTRL 65536              // 512 bytes: [0..3]=candCount [4..7]=T [8..11]=countAbove [12..15]=pairCount
#define OFF_CAND 66048              // 4 * 8192 * 8   = 262144
#define OFF_BOXES 328192            // 4 * 2048 * 7*4 = 229376
#define OFF_SCORE 557568            // 4 * 2048 * 4   = 32768
#define OFF_PAIRS 590336            // 4 * 4096 * 8   = 131072
// total ws use: 721408 bytes

__device__ __forceinline__ uint32_t f2key(float f) {
    uint32_t u = __float_as_uint(f);
    return (u & 0x80000000u) ? ~u : (u | 0x80000000u);  // monotone ascending
}

// ---------------- K1: per-batch histogram over top-12 key bits ----------------
__global__ void k_hist(const float* __restrict__ obj, uint32_t* __restrict__ hist) {
    __shared__ uint32_t h[NBUCKET];
    for (int j = threadIdx.x; j < NBUCKET; j += 256) h[j] = 0;
    __syncthreads();
    int base = blockIdx.x * 4096;                 // 4096-aligned => one (a,b) chunk
    int b = (base % HT) / LOCS;
    for (int k = 0; k < 16; ++k) {
        int g = base + k * 256 + threadIdx.x;
        uint32_t key = f2key(obj[g]);
        atomicAdd(&h[key >> 20], 1u);
    }
    __syncthreads();
    uint32_t* gh = hist + b * NBUCKET;
    for (int j = threadIdx.x; j < NBUCKET; j += 256)
        if (h[j]) atomicAdd(&gh[j], h[j]);
}

// ---------------- K2: find threshold bucket T and countAbove ----------------
__global__ void k_thresh(const uint32_t* __restrict__ hist, uint32_t* __restrict__ ctrl) {
    int b = blockIdx.x;
    const uint32_t* gh = hist + b * NBUCKET;
    __shared__ uint32_t s[64], sa[64];
    int l = threadIdx.x;                          // 64 threads
    uint32_t sum = 0;
    for (int j = 0; j < 64; ++j) sum += gh[l * 64 + j];
    s[l] = sum;
    __syncthreads();
    if (l == 0) {
        uint32_t acc = 0;
        for (int m = 63; m >= 0; --m) { sa[m] = acc; acc += s[m]; }
    }
    __syncthreads();
    if (sa[l] < PRE_NMS && sa[l] + s[l] >= PRE_NMS) {   // unique lane
        uint32_t cum = sa[l];
        for (int j = 63; j >= 0; --j) {
            uint32_t hv = gh[l * 64 + j];
            if (cum + hv >= PRE_NMS) { ctrl[4 + b] = (uint32_t)(l * 64 + j); ctrl[8 + b] = cum; break; }
            cum += hv;
        }
    }
}

// ---------------- K3: compact candidates with bucket >= T ----------------
__global__ void k_compact(const float* __restrict__ obj, uint32_t* __restrict__ ctrl,
                          unsigned long long* __restrict__ cand) {
    int base = blockIdx.x * 4096;
    int b = (base % HT) / LOCS;
    int a = base / HT;
    uint32_t T = ctrl[4 + b];
    for (int k = 0; k < 16; ++k) {
        int g = base + k * 256 + threadIdx.x;
        uint32_t key = f2key(obj[g]);
        if ((key >> 20) >= T) {
            int loc = g & (LOCS - 1);             // LOCS is pow2
            uint32_t i = (uint32_t)(loc * A_NUM + a);
            uint32_t pos = atomicAdd(&ctrl[b], 1u);
            if (pos < CAND_CAP)
                cand[(size_t)b * CAND_CAP + pos] =
                    ((unsigned long long)key << 32) | (uint32_t)(~i);
        }
    }
}

// ---------------- K4: per-batch bitonic sort (descending) + decode top-2048 ----------------
__global__ __launch_bounds__(1024) void k_sort_decode(
    const float* __restrict__ breg, const float* __restrict__ anchors,
    const uint32_t* __restrict__ ctrl, const unsigned long long* __restrict__ cand,
    float* __restrict__ boxes, float* __restrict__ scores) {
    __shared__ unsigned long long e[CAND_CAP];
    int b = blockIdx.x;
    uint32_t n = ctrl[b];
    if (n > CAND_CAP) n = CAND_CAP;
    unsigned np2 = 2048;
    while (np2 < n) np2 <<= 1;
    const unsigned long long* cb = cand + (size_t)b * CAND_CAP;
    for (unsigned j = threadIdx.x; j < np2; j += 1024) e[j] = (j < n) ? cb[j] : 0ull;
    __syncthreads();
    for (unsigned size = 2; size <= np2; size <<= 1)
        for (unsigned stride = size >> 1; stride > 0; stride >>= 1) {
            for (unsigned q = threadIdx.x; q < (np2 >> 1); q += 1024) {
                unsigned p = 2 * q - (q & (stride - 1));
                unsigned partner = p + stride;
                bool up = ((p & size) == 0);
                unsigned long long x = e[p], y = e[partner];
                if (up ? (x < y) : (x > y)) { e[p] = y; e[partner] = x; }  // descending
            }
            __syncthreads();
        }
    // decode top PRE_NMS
    for (unsigned j = threadIdx.x; j < PRE_NMS; j += 1024) {
        unsigned long long p = e[j];
        uint32_t key = (uint32_t)(p >> 32);
        uint32_t i = ~(uint32_t)p;
        uint32_t u = (key & 0x80000000u) ? (key ^ 0x80000000u) : ~key;
        float v = __uint_as_float(u);
        scores[b * PRE_NMS + j] = 1.0f / (1.0f + expf(-v));
        int a = (int)(i & 1);
        int loc = (int)(i >> 1);
        int t = b * LOCS + loc;
        float d[7];
        #pragma unroll
        for (int c = 0; c < 7; ++c) d[c] = breg[(size_t)(a * 7 + c) * HT + t];
        const float* anc = anchors + ((size_t)b * NPB + i) * 7;
        float xa = anc[0], ya = anc[1], za = anc[2];
        float wa = anc[3], la = anc[4], ha = anc[5], ra = anc[6];
        float diag = sqrtf(wa * wa + la * la);
        float* bx = boxes + ((size_t)b * PRE_NMS + j) * 7;
        bx[0] = d[0] * diag + xa;
        bx[1] = d[1] * diag + ya;
        bx[2] = d[2] * ha + za;
        bx[3] = expf(d[3]) * wa;
        bx[4] = expf(d[4]) * la;
        bx[5] = expf(d[5]) * ha;
        bx[6] = d[6] + ra;
    }
}

// ---------------- K5: find suppressing pairs (iou > thresh, j > i), tiled ----------------
// grid: BATCH * 32 blocks; block t owns i in [t*64, t*64+64); 256 threads stride j.
__global__ __launch_bounds__(256) void k_pairs(const float* __restrict__ boxes,
                                               uint32_t* __restrict__ pairCount,
                                               unsigned long long* __restrict__ pairs) {
    int b = blockIdx.x >> 5;
    int t = blockIdx.x & 31;
    int i0 = t * ITILE;
    __shared__ float bi[7][ITILE];   // x1,x2,y1,y2,z1,z2,vol
    if (threadIdx.x < ITILE) {
        const float* bx = boxes + ((size_t)b * PRE_NMS + i0 + threadIdx.x) * 7;
        float x = bx[0], y = bx[1], z = bx[2], w = bx[3], l = bx[4], h = bx[5];
        bi[0][threadIdx.x] = x - 0.5f * w; bi[1][threadIdx.x] = x + 0.5f * w;
        bi[2][threadIdx.x] = y - 0.5f * l; bi[3][threadIdx.x] = y + 0.5f * l;
        bi[4][threadIdx.x] = z;            bi[5][threadIdx.x] = z + h;
        bi[6][threadIdx.x] = fmaxf(w, 0.f) * fmaxf(l, 0.f) * fmaxf(h, 0.f);
    }
    __syncthreads();
    for (int j = i0 + 1 + (int)threadIdx.x; j < PRE_NMS; j += 256) {
        const float* bx = boxes + ((size_t)b * PRE_NMS + j) * 7;
        float x = bx[0], y = bx[1], z = bx[2], w = bx[3], l = bx[4], h = bx[5];
        float xj1 = x - 0.5f * w, xj2 = x + 0.5f * w;
        float yj1 = y - 0.5f * l, yj2 = y + 0.5f * l;
        float zj1 = z, zj2 = z + h;
        float vj = fmaxf(w, 0.f) * fmaxf(l, 0.f) * fmaxf(h, 0.f);
        int imax = j - i0; if (imax > ITILE) imax = ITILE;
        for (int ii = 0; ii < imax; ++ii) {
            float ix = fminf(bi[1][ii], xj2) - fmaxf(bi[0][ii], xj1); if (ix <= 0.f) continue;
            float iy = fminf(bi[3][ii], yj2) - fmaxf(bi[2][ii], yj1); if (iy <= 0.f) continue;
            float iz = fminf(bi[5][ii], zj2) - fmaxf(bi[4][ii], zj1); if (iz <= 0.f) continue;
            float inter = ix * iy * iz;
            float iou = inter / (bi[6][ii] + vj - inter + 1e-8f);
            if (iou > NMS_THRESH_F) {
                uint32_t pos = atomicAdd(&pairCount[b], 1u);
                if (pos < PAIR_CAP)
                    pairs[(size_t)b * PAIR_CAP + pos] =
                        ((unsigned long long)(uint32_t)(i0 + ii) << 32) | (uint32_t)j;
            }
        }
    }
}

// ---------------- K6: serial greedy scan over tiny pair list + emit output ----------------
__global__ __launch_bounds__(256) void k_scan_out(const float* __restrict__ boxes,
                                                  const float* __restrict__ scores,
                                                  const uint32_t* __restrict__ ctrl,
                                                  const unsigned long long* __restrict__ pairs,
                                                  float* __restrict__ out) {
    int b = blockIdx.x;
    __shared__ unsigned long long pl[PAIR_CAP];
    __shared__ unsigned long long keep[32];
    __shared__ uint32_t keptPre[33];
    uint32_t np = ctrl[12 + b];
    if (np > PAIR_CAP) np = PAIR_CAP;
    unsigned np2 = 64;
    while (np2 < np) np2 <<= 1;
    for (unsigned j = threadIdx.x; j < np2; j += 256)
        pl[j] = (j < np) ? pairs[(size_t)b * PAIR_CAP + j] : ~0ull;
    __syncthreads();
    for (unsigned size = 2; size <= np2; size <<= 1)
        for (unsigned stride = size >> 1; stride > 0; stride >>= 1) {
            for (unsigned q = threadIdx.x; q < (np2 >> 1); q += 256) {
                unsigned p = 2 * q - (q & (stride - 1));
                unsigned partner = p + stride;
                bool up = ((p & size) == 0);
                unsigned long long x = pl[p], y = pl[partner];
                if (up ? (x > y) : (x < y)) { pl[p] = y; pl[partner] = x; }  // ascending
            }
            __syncthreads();
        }
    if (threadIdx.x == 0) {
        for (int w = 0; w < 32; ++w) keep[w] = ~0ull;
        for (unsigned p = 0; p < np; ++p) {
            unsigned long long e = pl[p];
            uint32_t i = (uint32_t)(e >> 32), j = (uint32_t)e;
            if ((keep[i >> 6] >> (i & 63)) & 1ull)
                keep[j >> 6] &= ~(1ull << (j & 63));
        }
        uint32_t acc = 0;
        for (int w = 0; w < 32; ++w) { keptPre[w] = acc; acc += (uint32_t)__popcll(keep[w]); }
        keptPre[32] = acc;
    }
    __syncthreads();
    uint32_t totalKept = keptPre[32];
    for (int i = threadIdx.x; i < PRE_NMS; i += 256) {
        int w = i >> 6, bit = i & 63;
        unsigned long long kw = keep[w];
        uint32_t keptBefore = keptPre[w] + (uint32_t)__popcll(kw & ((1ull << bit) - 1ull));
        bool isKept = (kw >> bit) & 1ull;
        uint32_t pos = isKept ? keptBefore : (totalKept + (uint32_t)i - keptBefore);
        if (pos < POST_NMS) {
            float* o = out + ((size_t)b * POST_NMS + pos) * 8;
            const float* bx = boxes + ((size_t)b * PRE_NMS + i) * 7;
            #pragma unroll
            for (int c = 0; c < 7; ++c) o[c] = bx[c];
            o[7] = isKept ? scores[b * PRE_NMS + i] : 0.0f;
        }
    }
}

extern "C" void kernel_launch(void* const* d_in, const int* in_sizes, int n_in,
                              void* d_out, int out_size, void* d_ws, size_t ws_size,
                              hipStream_t stream) {
    const float* obj = (const float*)d_in[0];
    const float* breg = (const float*)d_in[1];
    const float* anchors = (const float*)d_in[2];
    float* out = (float*)d_out;
    char* ws = (char*)d_ws;
    uint32_t* hist = (uint32_t*)(ws + OFF_HIST);
    uint32_t* ctrl = (uint32_t*)(ws + OFF_CTRL);
    unsigned long long* cand = (unsigned long long*)(ws + OFF_CAND);
    float* boxes = (float*)(ws + OFF_BOXES);
    float* scores = (float*)(ws + OFF_SCORE);
    unsigned long long* pairs = (unsigned long long*)(ws + OFF_PAIRS);

    hipMemsetAsync(d_ws, 0, OFF_CAND, stream);  // zero hist + ctrl each call

    k_hist<<<TOTAL / 4096, 256, 0, stream>>>(obj, hist);
    k_thresh<<<BATCH, 64, 0, stream>>>(hist, ctrl);
    k_compact<<<TOTAL / 4096, 256, 0, stream>>>(obj, ctrl, cand);
    k_sort_decode<<<BATCH, 1024, 0, stream>>>(breg, anchors, ctrl, cand, boxes, scores);
    k_pairs<<<BATCH * 32, 256, 0, stream>>>(boxes, ctrl + 12, pairs);
    k_scan_out<<<BATCH, 256, 0, stream>>>(boxes, scores, ctrl, pairs, out);
}

// Round 3
// 186.709 us; speedup vs baseline: 2.6744x; 1.6125x over previous
//
#include <hip/hip_runtime.h>
#include <stdint.h>

#define BATCH 4
#define A_NUM 2
#define LOCS 262144                 // HT / B
#define HT (BATCH * LOCS)           // 1048576
#define NPB (LOCS * A_NUM)          // 524288 candidates per batch
#define TOTAL (A_NUM * HT)          // 2097152 objectness elements
#define PRE_NMS 2048
#define POST_NMS 512
#define NMS_THRESH_F 0.7f
#define NBUCKET 4096
#define NCOPY 8                     // hist copies per batch (atomic contention /8)
#define CAND_CAP 8192
#define PAIR_CAP 4096
#define ITILE 64

// workspace byte offsets
#define OFF_HIST 0                  // 4 * 8 * 4096 * 4 = 524288
#define OFF_CTRL 524288             // 512: [0..3]=candCount [4..7]=T [8..11]=countAbove [12..15]=pairCount
#define OFF_CAND 524800             // 4 * 8192 * 8   = 262144
#define OFF_BOXES 786944            // 4 * 2048 * 7*4 = 229376
#define OFF_SCORE 1016320           // 4 * 2048 * 4   = 32768
#define OFF_PAIRS 1049088           // 4 * 4096 * 8   = 131072
// total ws use: 1180160 bytes

__device__ __forceinline__ uint32_t f2key(float f) {
    uint32_t u = __float_as_uint(f);
    return (u & 0x80000000u) ? ~u : (u | 0x80000000u);  // monotone ascending
}

// ---------------- K1: per-batch histogram over top-12 key bits ----------------
// 512 blocks x 256 thr; each block owns a 4096-elem chunk (float4 loads),
// flushes its LDS hist into one of 8 per-batch global copies.
__global__ __launch_bounds__(256) void k_hist(const float4* __restrict__ obj4,
                                              uint32_t* __restrict__ hist) {
    __shared__ uint32_t h[NBUCKET];
    for (int j = threadIdx.x; j < NBUCKET; j += 256) h[j] = 0;
    __syncthreads();
    int base4 = blockIdx.x * 1024;               // float4 units
    int b = ((base4 * 4) % HT) / LOCS;
    for (int k = 0; k < 4; ++k) {
        float4 v = obj4[base4 + k * 256 + threadIdx.x];
        atomicAdd(&h[f2key(v.x) >> 20], 1u);
        atomicAdd(&h[f2key(v.y) >> 20], 1u);
        atomicAdd(&h[f2key(v.z) >> 20], 1u);
        atomicAdd(&h[f2key(v.w) >> 20], 1u);
    }
    __syncthreads();
    uint32_t* gh = hist + ((size_t)b * NCOPY + (blockIdx.x & (NCOPY - 1))) * NBUCKET;
    for (int j = threadIdx.x; j < NBUCKET; j += 256)
        if (h[j]) atomicAdd(&gh[j], h[j]);
}

// ---------------- K2: find threshold bucket T and countAbove ----------------
__global__ __launch_bounds__(64) void k_thresh(const uint32_t* __restrict__ hist,
                                               uint32_t* __restrict__ ctrl) {
    int b = blockIdx.x;
    const uint32_t* gh = hist + (size_t)b * NCOPY * NBUCKET;
    __shared__ uint32_t bs[NBUCKET];
    __shared__ uint32_t s[64], sa[64];
    int l = threadIdx.x;                          // 64 threads
    uint32_t sum = 0;
    for (int j = 0; j < 64; ++j) {
        uint32_t v = 0;
        #pragma unroll
        for (int c = 0; c < NCOPY; ++c) v += gh[(size_t)c * NBUCKET + l * 64 + j];
        bs[l * 64 + j] = v;
        sum += v;
    }
    s[l] = sum;
    __syncthreads();
    if (l == 0) {
        uint32_t acc = 0;
        for (int m = 63; m >= 0; --m) { sa[m] = acc; acc += s[m]; }
    }
    __syncthreads();
    if (sa[l] < PRE_NMS && sa[l] + s[l] >= PRE_NMS) {   // unique lane
        uint32_t cum = sa[l];
        for (int j = 63; j >= 0; --j) {
            uint32_t hv = bs[l * 64 + j];
            if (cum + hv >= PRE_NMS) { ctrl[4 + b] = (uint32_t)(l * 64 + j); ctrl[8 + b] = cum; break; }
            cum += hv;
        }
    }
}

// ---------------- K3: compact candidates with bucket >= T (block-staged) ----------------
__global__ __launch_bounds__(256) void k_compact(const float4* __restrict__ obj4,
                                                 uint32_t* __restrict__ ctrl,
                                                 unsigned long long* __restrict__ cand) {
    __shared__ uint32_t cnt, basepos;
    __shared__ unsigned long long buf[4096];      // block covers 4096 elems -> no overflow
    if (threadIdx.x == 0) cnt = 0;
    __syncthreads();
    int base4 = blockIdx.x * 1024;
    int belem = base4 * 4;
    int b = (belem % HT) / LOCS;
    int a = belem / HT;
    uint32_t T = ctrl[4 + b];
    for (int k = 0; k < 4; ++k) {
        int g4 = base4 + k * 256 + threadIdx.x;
        float4 v = obj4[g4];
        float vals[4] = {v.x, v.y, v.z, v.w};
        #pragma unroll
        for (int c = 0; c < 4; ++c) {
            uint32_t key = f2key(vals[c]);
            if ((key >> 20) >= T) {
                int g = g4 * 4 + c;
                int loc = g & (LOCS - 1);         // LOCS is pow2
                uint32_t i = (uint32_t)(loc * A_NUM + a);
                uint32_t pos = atomicAdd(&cnt, 1u);   // LDS atomic
                buf[pos] = ((unsigned long long)key << 32) | (uint32_t)(~i);
            }
        }
    }
    __syncthreads();
    if (threadIdx.x == 0) basepos = atomicAdd(&ctrl[b], cnt);  // one global atomic/block
    __syncthreads();
    uint32_t n = cnt, bp = basepos;
    for (uint32_t j = threadIdx.x; j < n; j += 256) {
        uint32_t p = bp + j;
        if (p < CAND_CAP) cand[(size_t)b * CAND_CAP + p] = buf[j];
    }
}

// ---------------- K4: per-batch bitonic sort (descending) + decode top-2048 ----------------
__global__ __launch_bounds__(1024) void k_sort_decode(
    const float* __restrict__ breg, const float* __restrict__ anchors,
    const uint32_t* __restrict__ ctrl, const unsigned long long* __restrict__ cand,
    float* __restrict__ boxes, float* __restrict__ scores) {
    __shared__ unsigned long long e[CAND_CAP];
    int b = blockIdx.x;
    uint32_t n = ctrl[b];
    if (n > CAND_CAP) n = CAND_CAP;
    unsigned np2 = 2048;
    while (np2 < n) np2 <<= 1;
    const unsigned long long* cb = cand + (size_t)b * CAND_CAP;
    for (unsigned j = threadIdx.x; j < np2; j += 1024) e[j] = (j < n) ? cb[j] : 0ull;
    __syncthreads();
    for (unsigned size = 2; size <= np2; size <<= 1)
        for (unsigned stride = size >> 1; stride > 0; stride >>= 1) {
            for (unsigned q = threadIdx.x; q < (np2 >> 1); q += 1024) {
                unsigned p = 2 * q - (q & (stride - 1));
                unsigned partner = p + stride;
                bool up = ((p & size) == 0);
                unsigned long long x = e[p], y = e[partner];
                if (up ? (x < y) : (x > y)) { e[p] = y; e[partner] = x; }  // descending
            }
            __syncthreads();
        }
    // decode top PRE_NMS
    for (unsigned j = threadIdx.x; j < PRE_NMS; j += 1024) {
        unsigned long long p = e[j];
        uint32_t key = (uint32_t)(p >> 32);
        uint32_t i = ~(uint32_t)p;
        uint32_t u = (key & 0x80000000u) ? (key ^ 0x80000000u) : ~key;
        float v = __uint_as_float(u);
        scores[b * PRE_NMS + j] = 1.0f / (1.0f + expf(-v));
        int a = (int)(i & 1);
        int loc = (int)(i >> 1);
        int t = b * LOCS + loc;
        float d[7];
        #pragma unroll
        for (int c = 0; c < 7; ++c) d[c] = breg[(size_t)(a * 7 + c) * HT + t];
        const float* anc = anchors + ((size_t)b * NPB + i) * 7;
        float xa = anc[0], ya = anc[1], za = anc[2];
        float wa = anc[3], la = anc[4], ha = anc[5], ra = anc[6];
        float diag = sqrtf(wa * wa + la * la);
        float* bx = boxes + ((size_t)b * PRE_NMS + j) * 7;
        bx[0] = d[0] * diag + xa;
        bx[1] = d[1] * diag + ya;
        bx[2] = d[2] * ha + za;
        bx[3] = expf(d[3]) * wa;
        bx[4] = expf(d[4]) * la;
        bx[5] = expf(d[5]) * ha;
        bx[6] = d[6] + ra;
    }
}

// ---------------- K5: find suppressing pairs (iou > thresh, j > i), tiled ----------------
__global__ __launch_bounds__(256) void k_pairs(const float* __restrict__ boxes,
                                               uint32_t* __restrict__ pairCount,
                                               unsigned long long* __restrict__ pairs) {
    int b = blockIdx.x >> 5;
    int t = blockIdx.x & 31;
    int i0 = t * ITILE;
    __shared__ float bi[7][ITILE];   // x1,x2,y1,y2,z1,z2,vol
    if (threadIdx.x < ITILE) {
        const float* bx = boxes + ((size_t)b * PRE_NMS + i0 + threadIdx.x) * 7;
        float x = bx[0], y = bx[1], z = bx[2], w = bx[3], l = bx[4], h = bx[5];
        bi[0][threadIdx.x] = x - 0.5f * w; bi[1][threadIdx.x] = x + 0.5f * w;
        bi[2][threadIdx.x] = y - 0.5f * l; bi[3][threadIdx.x] = y + 0.5f * l;
        bi[4][threadIdx.x] = z;            bi[5][threadIdx.x] = z + h;
        bi[6][threadIdx.x] = fmaxf(w, 0.f) * fmaxf(l, 0.f) * fmaxf(h, 0.f);
    }
    __syncthreads();
    for (int j = i0 + 1 + (int)threadIdx.x; j < PRE_NMS; j += 256) {
        const float* bx = boxes + ((size_t)b * PRE_NMS + j) * 7;
        float x = bx[0], y = bx[1], z = bx[2], w = bx[3], l = bx[4], h = bx[5];
        float xj1 = x - 0.5f * w, xj2 = x + 0.5f * w;
        float yj1 = y - 0.5f * l, yj2 = y + 0.5f * l;
        float zj1 = z, zj2 = z + h;
        float vj = fmaxf(w, 0.f) * fmaxf(l, 0.f) * fmaxf(h, 0.f);
        int imax = j - i0; if (imax > ITILE) imax = ITILE;
        for (int ii = 0; ii < imax; ++ii) {
            float ix = fminf(bi[1][ii], xj2) - fmaxf(bi[0][ii], xj1); if (ix <= 0.f) continue;
            float iy = fminf(bi[3][ii], yj2) - fmaxf(bi[2][ii], yj1); if (iy <= 0.f) continue;
            float iz = fminf(bi[5][ii], zj2) - fmaxf(bi[4][ii], zj1); if (iz <= 0.f) continue;
            float inter = ix * iy * iz;
            float iou = inter / (bi[6][ii] + vj - inter + 1e-8f);
            if (iou > NMS_THRESH_F) {
                uint32_t pos = atomicAdd(&pairCount[b], 1u);
                if (pos < PAIR_CAP)
                    pairs[(size_t)b * PAIR_CAP + pos] =
                        ((unsigned long long)(uint32_t)(i0 + ii) << 32) | (uint32_t)j;
            }
        }
    }
}

// ---------------- K6: serial greedy scan over tiny pair list + emit output ----------------
__global__ __launch_bounds__(256) void k_scan_out(const float* __restrict__ boxes,
                                                  const float* __restrict__ scores,
                                                  const uint32_t* __restrict__ ctrl,
                                                  const unsigned long long* __restrict__ pairs,
                                                  float* __restrict__ out) {
    int b = blockIdx.x;
    __shared__ unsigned long long pl[PAIR_CAP];
    __shared__ unsigned long long keep[32];
    __shared__ uint32_t keptPre[33];
    uint32_t np = ctrl[12 + b];
    if (np > PAIR_CAP) np = PAIR_CAP;
    unsigned np2 = 64;
    while (np2 < np) np2 <<= 1;
    for (unsigned j = threadIdx.x; j < np2; j += 256)
        pl[j] = (j < np) ? pairs[(size_t)b * PAIR_CAP + j] : ~0ull;
    __syncthreads();
    for (unsigned size = 2; size <= np2; size <<= 1)
        for (unsigned stride = size >> 1; stride > 0; stride >>= 1) {
            for (unsigned q = threadIdx.x; q < (np2 >> 1); q += 256) {
                unsigned p = 2 * q - (q & (stride - 1));
                unsigned partner = p + stride;
                bool up = ((p & size) == 0);
                unsigned long long x = pl[p], y = pl[partner];
                if (up ? (x > y) : (x < y)) { pl[p] = y; pl[partner] = x; }  // ascending
            }
            __syncthreads();
        }
    if (threadIdx.x == 0) {
        for (int w = 0; w < 32; ++w) keep[w] = ~0ull;
        for (unsigned p = 0; p < np; ++p) {
            unsigned long long e = pl[p];
            uint32_t i = (uint32_t)(e >> 32), j = (uint32_t)e;
            if ((keep[i >> 6] >> (i & 63)) & 1ull)
                keep[j >> 6] &= ~(1ull << (j & 63));
        }
        uint32_t acc = 0;
        for (int w = 0; w < 32; ++w) { keptPre[w] = acc; acc += (uint32_t)__popcll(keep[w]); }
        keptPre[32] = acc;
    }
    __syncthreads();
    uint32_t totalKept = keptPre[32];
    for (int i = threadIdx.x; i < PRE_NMS; i += 256) {
        int w = i >> 6, bit = i & 63;
        unsigned long long kw = keep[w];
        uint32_t keptBefore = keptPre[w] + (uint32_t)__popcll(kw & ((1ull << bit) - 1ull));
        bool isKept = (kw >> bit) & 1ull;
        uint32_t pos = isKept ? keptBefore : (totalKept + (uint32_t)i - keptBefore);
        if (pos < POST_NMS) {
            float* o = out + ((size_t)b * POST_NMS + pos) * 8;
            const float* bx = boxes + ((size_t)b * PRE_NMS + i) * 7;
            #pragma unroll
            for (int c = 0; c < 7; ++c) o[c] = bx[c];
            o[7] = isKept ? scores[b * PRE_NMS + i] : 0.0f;
        }
    }
}

extern "C" void kernel_launch(void* const* d_in, const int* in_sizes, int n_in,
                              void* d_out, int out_size, void* d_ws, size_t ws_size,
                              hipStream_t stream) {
    const float* obj = (const float*)d_in[0];
    const float* breg = (const float*)d_in[1];
    const float* anchors = (const float*)d_in[2];
    float* out = (float*)d_out;
    char* ws = (char*)d_ws;
    uint32_t* hist = (uint32_t*)(ws + OFF_HIST);
    uint32_t* ctrl = (uint32_t*)(ws + OFF_CTRL);
    unsigned long long* cand = (unsigned long long*)(ws + OFF_CAND);
    float* boxes = (float*)(ws + OFF_BOXES);
    float* scores = (float*)(ws + OFF_SCORE);
    unsigned long long* pairs = (unsigned long long*)(ws + OFF_PAIRS);

    hipMemsetAsync(d_ws, 0, OFF_CAND, stream);  // zero hist + ctrl each call

    k_hist<<<TOTAL / 4096, 256, 0, stream>>>((const float4*)obj, hist);
    k_thresh<<<BATCH, 64, 0, stream>>>(hist, ctrl);
    k_compact<<<TOTAL / 4096, 256, 0, stream>>>((const float4*)obj, ctrl, cand);
    k_sort_decode<<<BATCH, 1024, 0, stream>>>(breg, anchors, ctrl, cand, boxes, scores);
    k_pairs<<<BATCH * 32, 256, 0, stream>>>(boxes, ctrl + 12, pairs);
    k_scan_out<<<BATCH, 256, 0, stream>>>(boxes, scores, ctrl, pairs, out);
}

// Round 4
// 119.659 us; speedup vs baseline: 4.1731x; 1.5603x over previous
//
#include <hip/hip_runtime.h>
#include <stdint.h>

#define BATCH 4
#define A_NUM 2
#define LOCS 262144                 // HT / B
#define HT (BATCH * LOCS)           // 1048576
#define NPB (LOCS * A_NUM)          // 524288 candidates per batch
#define TOTAL (A_NUM * HT)          // 2097152 objectness elements
#define PRE_NMS 2048
#define POST_NMS 512
#define NMS_THRESH_F 0.7f
#define NBUCKET 4096
#define NCOPY 8                     // hist copies per batch (atomic contention /8)
#define CAND_CAP 8192
#define PAIR_CAP 4096
#define PTILE 64
#define NT (PRE_NMS / PTILE)        // 32

// workspace byte offsets
#define OFF_HIST 0                  // 4 * 8 * 4096 * 4 = 524288
#define OFF_CTRL 524288             // 512: [0..3]=candCount [4..7]=T [8..11]=countAbove [12..15]=pairCount
#define OFF_CAND 524800             // 4 * 8192 * 8   = 262144
#define OFF_BOXES 786944            // 4 * 2048 * 7*4 = 229376
#define OFF_SCORE 1016320           // 4 * 2048 * 4   = 32768
#define OFF_PAIRS 1049088           // 4 * 4096 * 8   = 131072
#define OFF_EXT 1180160             // 4 * 2048 * 8*4 = 262144
// total ws use: 1442304 bytes

__device__ __forceinline__ uint32_t f2key(float f) {
    uint32_t u = __float_as_uint(f);
    return (u & 0x80000000u) ? ~u : (u | 0x80000000u);  // monotone ascending
}

// ---------------- K1: per-batch histogram over top-12 key bits ----------------
__global__ __launch_bounds__(256) void k_hist(const float4* __restrict__ obj4,
                                              uint32_t* __restrict__ hist) {
    __shared__ uint32_t h[NBUCKET];
    for (int j = threadIdx.x; j < NBUCKET; j += 256) h[j] = 0;
    __syncthreads();
    int base4 = blockIdx.x * 1024;               // float4 units
    int b = ((base4 * 4) % HT) / LOCS;
    for (int k = 0; k < 4; ++k) {
        float4 v = obj4[base4 + k * 256 + threadIdx.x];
        atomicAdd(&h[f2key(v.x) >> 20], 1u);
        atomicAdd(&h[f2key(v.y) >> 20], 1u);
        atomicAdd(&h[f2key(v.z) >> 20], 1u);
        atomicAdd(&h[f2key(v.w) >> 20], 1u);
    }
    __syncthreads();
    uint32_t* gh = hist + ((size_t)b * NCOPY + (blockIdx.x & (NCOPY - 1))) * NBUCKET;
    for (int j = threadIdx.x; j < NBUCKET; j += 256)
        if (h[j]) atomicAdd(&gh[j], h[j]);
}

// ---------------- K2: find threshold bucket T and countAbove ----------------
__global__ __launch_bounds__(64) void k_thresh(const uint32_t* __restrict__ hist,
                                               uint32_t* __restrict__ ctrl) {
    int b = blockIdx.x;
    const uint32_t* gh = hist + (size_t)b * NCOPY * NBUCKET;
    __shared__ uint32_t bs[NBUCKET];
    __shared__ uint32_t s[64], sa[64];
    int l = threadIdx.x;                          // 64 threads
    uint32_t sum = 0;
    for (int j = 0; j < 64; ++j) {
        uint32_t v = 0;
        #pragma unroll
        for (int c = 0; c < NCOPY; ++c) v += gh[(size_t)c * NBUCKET + l * 64 + j];
        bs[l * 64 + j] = v;
        sum += v;
    }
    s[l] = sum;
    __syncthreads();
    if (l == 0) {
        uint32_t acc = 0;
        for (int m = 63; m >= 0; --m) { sa[m] = acc; acc += s[m]; }
    }
    __syncthreads();
    if (sa[l] < PRE_NMS && sa[l] + s[l] >= PRE_NMS) {   // unique lane
        uint32_t cum = sa[l];
        for (int j = 63; j >= 0; --j) {
            uint32_t hv = bs[l * 64 + j];
            if (cum + hv >= PRE_NMS) { ctrl[4 + b] = (uint32_t)(l * 64 + j); ctrl[8 + b] = cum; break; }
            cum += hv;
        }
    }
}

// ---------------- K3: compact candidates with bucket >= T (block-staged) ----------------
__global__ __launch_bounds__(256) void k_compact(const float4* __restrict__ obj4,
                                                 uint32_t* __restrict__ ctrl,
                                                 unsigned long long* __restrict__ cand) {
    __shared__ uint32_t cnt, basepos;
    __shared__ unsigned long long buf[4096];      // block covers 4096 elems -> no overflow
    if (threadIdx.x == 0) cnt = 0;
    __syncthreads();
    int base4 = blockIdx.x * 1024;
    int belem = base4 * 4;
    int b = (belem % HT) / LOCS;
    int a = belem / HT;
    uint32_t T = ctrl[4 + b];
    for (int k = 0; k < 4; ++k) {
        int g4 = base4 + k * 256 + threadIdx.x;
        float4 v = obj4[g4];
        float vals[4] = {v.x, v.y, v.z, v.w};
        #pragma unroll
        for (int c = 0; c < 4; ++c) {
            uint32_t key = f2key(vals[c]);
            if ((key >> 20) >= T) {
                int g = g4 * 4 + c;
                int loc = g & (LOCS - 1);         // LOCS is pow2
                uint32_t i = (uint32_t)(loc * A_NUM + a);
                uint32_t pos = atomicAdd(&cnt, 1u);   // LDS atomic
                buf[pos] = ((unsigned long long)key << 32) | (uint32_t)(~i);
            }
        }
    }
    __syncthreads();
    if (threadIdx.x == 0) basepos = atomicAdd(&ctrl[b], cnt);  // one global atomic/block
    __syncthreads();
    uint32_t n = cnt, bp = basepos;
    for (uint32_t j = threadIdx.x; j < n; j += 256) {
        uint32_t p = bp + j;
        if (p < CAND_CAP) cand[(size_t)b * CAND_CAP + p] = buf[j];
    }
}

// ---------------- K4: per-batch bitonic sort (descending) + decode top-2048 ----------------
__global__ __launch_bounds__(1024) void k_sort_decode(
    const float* __restrict__ breg, const float* __restrict__ anchors,
    const uint32_t* __restrict__ ctrl, const unsigned long long* __restrict__ cand,
    float* __restrict__ boxes, float* __restrict__ scores, float* __restrict__ ext) {
    __shared__ unsigned long long e[CAND_CAP];
    int b = blockIdx.x;
    uint32_t n = ctrl[b];
    if (n > CAND_CAP) n = CAND_CAP;
    unsigned np2 = 2048;
    while (np2 < n) np2 <<= 1;
    const unsigned long long* cb = cand + (size_t)b * CAND_CAP;
    for (unsigned j = threadIdx.x; j < np2; j += 1024) e[j] = (j < n) ? cb[j] : 0ull;
    __syncthreads();
    for (unsigned size = 2; size <= np2; size <<= 1)
        for (unsigned stride = size >> 1; stride > 0; stride >>= 1) {
            for (unsigned q = threadIdx.x; q < (np2 >> 1); q += 1024) {
                unsigned p = 2 * q - (q & (stride - 1));
                unsigned partner = p + stride;
                bool up = ((p & size) == 0);
                unsigned long long x = e[p], y = e[partner];
                if (up ? (x < y) : (x > y)) { e[p] = y; e[partner] = x; }  // descending
            }
            __syncthreads();
        }
    // decode top PRE_NMS
    for (unsigned j = threadIdx.x; j < PRE_NMS; j += 1024) {
        unsigned long long p = e[j];
        uint32_t key = (uint32_t)(p >> 32);
        uint32_t i = ~(uint32_t)p;
        uint32_t u = (key & 0x80000000u) ? (key ^ 0x80000000u) : ~key;
        float v = __uint_as_float(u);
        scores[b * PRE_NMS + j] = 1.0f / (1.0f + expf(-v));
        int a = (int)(i & 1);
        int loc = (int)(i >> 1);
        int t = b * LOCS + loc;
        float d[7];
        #pragma unroll
        for (int c = 0; c < 7; ++c) d[c] = breg[(size_t)(a * 7 + c) * HT + t];
        const float* anc = anchors + ((size_t)b * NPB + i) * 7;
        float xa = anc[0], ya = anc[1], za = anc[2];
        float wa = anc[3], la = anc[4], ha = anc[5], ra = anc[6];
        float diag = sqrtf(wa * wa + la * la);
        float X = d[0] * diag + xa;
        float Y = d[1] * diag + ya;
        float Z = d[2] * ha + za;
        float W = expf(d[3]) * wa;
        float L = expf(d[4]) * la;
        float H = expf(d[5]) * ha;
        float R = d[6] + ra;
        float* bx = boxes + ((size_t)b * PRE_NMS + j) * 7;
        bx[0] = X; bx[1] = Y; bx[2] = Z; bx[3] = W; bx[4] = L; bx[5] = H; bx[6] = R;
        float4* ep = (float4*)(ext + ((size_t)b * PRE_NMS + j) * 8);
        ep[0] = make_float4(X - 0.5f * W, X + 0.5f * W, Y - 0.5f * L, Y + 0.5f * L);
        ep[1] = make_float4(Z, Z + H,
                            fmaxf(W, 0.f) * fmaxf(L, 0.f) * fmaxf(H, 0.f), 0.f);
    }
}

// ---------------- K5: suppressing pairs, 64x64 tile grid ----------------
// grid: BATCH * NT * NT blocks, 64 threads; lower-triangle tiles exit.
__global__ __launch_bounds__(64) void k_pairs(const float* __restrict__ ext,
                                              uint32_t* __restrict__ pairCount,
                                              unsigned long long* __restrict__ pairs) {
    int b = blockIdx.x / (NT * NT);
    int r = blockIdx.x % (NT * NT);
    int ti = r / NT, tj = r % NT;
    if (tj < ti) return;
    __shared__ float bi[PTILE][8];
    const float* eb = ext + (size_t)b * PRE_NMS * 8;
    {   // stage i-tile extents: 128 float4s, coalesced
        const float4* src = (const float4*)(eb + (size_t)ti * PTILE * 8);
        float4* dst = (float4*)&bi[0][0];
        dst[threadIdx.x] = src[threadIdx.x];
        dst[threadIdx.x + 64] = src[threadIdx.x + 64];
    }
    __syncthreads();
    int j = tj * PTILE + threadIdx.x;
    const float4* jp = (const float4*)(eb + (size_t)j * 8);
    float4 j0 = jp[0], j1 = jp[1];
    float xj1 = j0.x, xj2 = j0.y, yj1 = j0.z, yj2 = j0.w;
    float zj1 = j1.x, zj2 = j1.y, vj = j1.z;
    int iimax = (ti == tj) ? (int)threadIdx.x : PTILE;   // enforce i < j
    for (int ii = 0; ii < iimax; ++ii) {
        float ix = fminf(bi[ii][1], xj2) - fmaxf(bi[ii][0], xj1); if (ix <= 0.f) continue;
        float iy = fminf(bi[ii][3], yj2) - fmaxf(bi[ii][2], yj1); if (iy <= 0.f) continue;
        float iz = fminf(bi[ii][5], zj2) - fmaxf(bi[ii][4], zj1); if (iz <= 0.f) continue;
        float inter = ix * iy * iz;
        float iou = inter / (bi[ii][6] + vj - inter + 1e-8f);
        if (iou > NMS_THRESH_F) {
            uint32_t pos = atomicAdd(&pairCount[b], 1u);
            if (pos < PAIR_CAP)
                pairs[(size_t)b * PAIR_CAP + pos] =
                    ((unsigned long long)(uint32_t)(ti * PTILE + ii) << 32) | (uint32_t)j;
        }
    }
}

// ---------------- K6: serial greedy scan over tiny pair list + emit output ----------------
__global__ __launch_bounds__(256) void k_scan_out(const float* __restrict__ boxes,
                                                  const float* __restrict__ scores,
                                                  const uint32_t* __restrict__ ctrl,
                                                  const unsigned long long* __restrict__ pairs,
                                                  float* __restrict__ out) {
    int b = blockIdx.x;
    __shared__ unsigned long long pl[PAIR_CAP];
    __shared__ unsigned long long keep[32];
    __shared__ uint32_t keptPre[33];
    uint32_t np = ctrl[12 + b];
    if (np > PAIR_CAP) np = PAIR_CAP;
    unsigned np2 = 64;
    while (np2 < np) np2 <<= 1;
    for (unsigned j = threadIdx.x; j < np2; j += 256)
        pl[j] = (j < np) ? pairs[(size_t)b * PAIR_CAP + j] : ~0ull;
    __syncthreads();
    for (unsigned size = 2; size <= np2; size <<= 1)
        for (unsigned stride = size >> 1; stride > 0; stride >>= 1) {
            for (unsigned q = threadIdx.x; q < (np2 >> 1); q += 256) {
                unsigned p = 2 * q - (q & (stride - 1));
                unsigned partner = p + stride;
                bool up = ((p & size) == 0);
                unsigned long long x = pl[p], y = pl[partner];
                if (up ? (x > y) : (x < y)) { pl[p] = y; pl[partner] = x; }  // ascending
            }
            __syncthreads();
        }
    if (threadIdx.x == 0) {
        for (int w = 0; w < 32; ++w) keep[w] = ~0ull;
        for (unsigned p = 0; p < np; ++p) {
            unsigned long long e = pl[p];
            uint32_t i = (uint32_t)(e >> 32), j = (uint32_t)e;
            if ((keep[i >> 6] >> (i & 63)) & 1ull)
                keep[j >> 6] &= ~(1ull << (j & 63));
        }
        uint32_t acc = 0;
        for (int w = 0; w < 32; ++w) { keptPre[w] = acc; acc += (uint32_t)__popcll(keep[w]); }
        keptPre[32] = acc;
    }
    __syncthreads();
    uint32_t totalKept = keptPre[32];
    for (int i = threadIdx.x; i < PRE_NMS; i += 256) {
        int w = i >> 6, bit = i & 63;
        unsigned long long kw = keep[w];
        uint32_t keptBefore = keptPre[w] + (uint32_t)__popcll(kw & ((1ull << bit) - 1ull));
        bool isKept = (kw >> bit) & 1ull;
        uint32_t pos = isKept ? keptBefore : (totalKept + (uint32_t)i - keptBefore);
        if (pos < POST_NMS) {
            float* o = out + ((size_t)b * POST_NMS + pos) * 8;
            const float* bx = boxes + ((size_t)b * PRE_NMS + i) * 7;
            #pragma unroll
            for (int c = 0; c < 7; ++c) o[c] = bx[c];
            o[7] = isKept ? scores[b * PRE_NMS + i] : 0.0f;
        }
    }
}

extern "C" void kernel_launch(void* const* d_in, const int* in_sizes, int n_in,
                              void* d_out, int out_size, void* d_ws, size_t ws_size,
                              hipStream_t stream) {
    const float* obj = (const float*)d_in[0];
    const float* breg = (const float*)d_in[1];
    const float* anchors = (const float*)d_in[2];
    float* out = (float*)d_out;
    char* ws = (char*)d_ws;
    uint32_t* hist = (uint32_t*)(ws + OFF_HIST);
    uint32_t* ctrl = (uint32_t*)(ws + OFF_CTRL);
    unsigned long long* cand = (unsigned long long*)(ws + OFF_CAND);
    float* boxes = (float*)(ws + OFF_BOXES);
    float* scores = (float*)(ws + OFF_SCORE);
    unsigned long long* pairs = (unsigned long long*)(ws + OFF_PAIRS);
    float* ext = (float*)(ws + OFF_EXT);

    hipMemsetAsync(d_ws, 0, OFF_CAND, stream);  // zero hist + ctrl each call

    k_hist<<<TOTAL / 4096, 256, 0, stream>>>((const float4*)obj, hist);
    k_thresh<<<BATCH, 64, 0, stream>>>(hist, ctrl);
    k_compact<<<TOTAL / 4096, 256, 0, stream>>>((const float4*)obj, ctrl, cand);
    k_sort_decode<<<BATCH, 1024, 0, stream>>>(breg, anchors, ctrl, cand, boxes, scores, ext);
    k_pairs<<<BATCH * NT * NT, 64, 0, stream>>>(ext, ctrl + 12, pairs);
    k_scan_out<<<BATCH, 256, 0, stream>>>(boxes, scores, ctrl, pairs, out);
}

// Round 5
// 110.838 us; speedup vs baseline: 4.5052x; 1.0796x over previous
//
#include <hip/hip_runtime.h>
#include <stdint.h>

#define BATCH 4
#define A_NUM 2
#define LOCS 262144                 // HT / B
#define HT (BATCH * LOCS)           // 1048576
#define NPB (LOCS * A_NUM)          // 524288 candidates per batch
#define TOTAL (A_NUM * HT)          // 2097152 objectness elements
#define PRE_NMS 2048
#define POST_NMS 512
#define NMS_THRESH_F 0.7f
#define NBUCKET 4096
#define NCOPY 8                     // hist copies per batch (atomic contention /8)
#define CAND_CAP 8192
#define PAIR_CAP 4096
#define PTILE 64
#define NT (PRE_NMS / PTILE)        // 32
#define RANK_TPB 128
#define RANK_BPB (CAND_CAP / RANK_TPB)   // 64 blocks per batch

// workspace byte offsets
#define OFF_HIST 0                  // 4 * 8 * 4096 * 4 = 524288
#define OFF_CTRL 524288             // 512: [0..3]=candCount [4..7]=T [8..11]=countAbove [12..15]=pairCount
#define OFF_CAND 524800             // 4 * 8192 * 8   = 262144
#define OFF_BOXES 786944            // 4 * 2048 * 7*4 = 229376
#define OFF_SCORE 1016320           // 4 * 2048 * 4   = 32768
#define OFF_PAIRS 1049088           // 4 * 4096 * 8   = 131072
#define OFF_EXT 1180160             // 4 * 2048 * 8*4 = 262144
// total ws use: 1442304 bytes

__device__ __forceinline__ uint32_t f2key(float f) {
    uint32_t u = __float_as_uint(f);
    return (u & 0x80000000u) ? ~u : (u | 0x80000000u);  // monotone ascending
}

// ---------------- K1: per-batch histogram over top-12 key bits ----------------
__global__ __launch_bounds__(256) void k_hist(const float4* __restrict__ obj4,
                                              uint32_t* __restrict__ hist) {
    __shared__ uint32_t h[NBUCKET];
    for (int j = threadIdx.x; j < NBUCKET; j += 256) h[j] = 0;
    __syncthreads();
    int base4 = blockIdx.x * 1024;               // float4 units
    int b = ((base4 * 4) % HT) / LOCS;
    for (int k = 0; k < 4; ++k) {
        float4 v = obj4[base4 + k * 256 + threadIdx.x];
        atomicAdd(&h[f2key(v.x) >> 20], 1u);
        atomicAdd(&h[f2key(v.y) >> 20], 1u);
        atomicAdd(&h[f2key(v.z) >> 20], 1u);
        atomicAdd(&h[f2key(v.w) >> 20], 1u);
    }
    __syncthreads();
    uint32_t* gh = hist + ((size_t)b * NCOPY + (blockIdx.x & (NCOPY - 1))) * NBUCKET;
    for (int j = threadIdx.x; j < NBUCKET; j += 256)
        if (h[j]) atomicAdd(&gh[j], h[j]);
}

// ---------------- K2: find threshold bucket T and countAbove ----------------
__global__ __launch_bounds__(64) void k_thresh(const uint32_t* __restrict__ hist,
                                               uint32_t* __restrict__ ctrl) {
    int b = blockIdx.x;
    const uint32_t* gh = hist + (size_t)b * NCOPY * NBUCKET;
    __shared__ uint32_t bs[NBUCKET];
    __shared__ uint32_t s[64], sa[64];
    int l = threadIdx.x;                          // 64 threads
    uint32_t sum = 0;
    for (int j = 0; j < 64; ++j) {
        uint32_t v = 0;
        #pragma unroll
        for (int c = 0; c < NCOPY; ++c) v += gh[(size_t)c * NBUCKET + l * 64 + j];
        bs[l * 64 + j] = v;
        sum += v;
    }
    s[l] = sum;
    __syncthreads();
    if (l == 0) {
        uint32_t acc = 0;
        for (int m = 63; m >= 0; --m) { sa[m] = acc; acc += s[m]; }
    }
    __syncthreads();
    if (sa[l] < PRE_NMS && sa[l] + s[l] >= PRE_NMS) {   // unique lane
        uint32_t cum = sa[l];
        for (int j = 63; j >= 0; --j) {
            uint32_t hv = bs[l * 64 + j];
            if (cum + hv >= PRE_NMS) { ctrl[4 + b] = (uint32_t)(l * 64 + j); ctrl[8 + b] = cum; break; }
            cum += hv;
        }
    }
}

// ---------------- K3: compact candidates with bucket >= T (block-staged) ----------------
__global__ __launch_bounds__(256) void k_compact(const float4* __restrict__ obj4,
                                                 uint32_t* __restrict__ ctrl,
                                                 unsigned long long* __restrict__ cand) {
    __shared__ uint32_t cnt, basepos;
    __shared__ unsigned long long buf[4096];      // block covers 4096 elems -> no overflow
    if (threadIdx.x == 0) cnt = 0;
    __syncthreads();
    int base4 = blockIdx.x * 1024;
    int belem = base4 * 4;
    int b = (belem % HT) / LOCS;
    int a = belem / HT;
    uint32_t T = ctrl[4 + b];
    for (int k = 0; k < 4; ++k) {
        int g4 = base4 + k * 256 + threadIdx.x;
        float4 v = obj4[g4];
        float vals[4] = {v.x, v.y, v.z, v.w};
        #pragma unroll
        for (int c = 0; c < 4; ++c) {
            uint32_t key = f2key(vals[c]);
            if ((key >> 20) >= T) {
                int g = g4 * 4 + c;
                int loc = g & (LOCS - 1);         // LOCS is pow2
                uint32_t i = (uint32_t)(loc * A_NUM + a);
                uint32_t pos = atomicAdd(&cnt, 1u);   // LDS atomic
                buf[pos] = ((unsigned long long)key << 32) | (uint32_t)(~i);
            }
        }
    }
    __syncthreads();
    if (threadIdx.x == 0) basepos = atomicAdd(&ctrl[b], cnt);  // one global atomic/block
    __syncthreads();
    uint32_t n = cnt, bp = basepos;
    for (uint32_t j = threadIdx.x; j < n; j += 256) {
        uint32_t p = bp + j;
        if (p < CAND_CAP) cand[(size_t)b * CAND_CAP + p] = buf[j];
    }
}

// ---------------- K4: rank-by-count (values unique) + decode at rank ----------------
// grid: BATCH * RANK_BPB blocks x 128 thr. Each thread owns one candidate;
// rank = #{values greater}; decode directly into position `rank` if < PRE_NMS.
__global__ __launch_bounds__(RANK_TPB) void k_rank(
    const float* __restrict__ breg, const float* __restrict__ anchors,
    const uint32_t* __restrict__ ctrl, const unsigned long long* __restrict__ cand,
    float* __restrict__ boxes, float* __restrict__ scores, float* __restrict__ ext) {
    int b = blockIdx.x / RANK_BPB;
    int t = blockIdx.x % RANK_BPB;
    uint32_t n = ctrl[b];
    if (n > CAND_CAP) n = CAND_CAP;
    if ((uint32_t)(t * RANK_TPB) >= n) return;    // whole block idle
    __shared__ unsigned long long ch[RANK_TPB];
    const unsigned long long* cb = cand + (size_t)b * CAND_CAP;
    uint32_t myIdx = t * RANK_TPB + threadIdx.x;
    unsigned long long my = (myIdx < n) ? cb[myIdx] : 0ull;
    uint32_t rank = 0;
    for (uint32_t c0 = 0; c0 < n; c0 += RANK_TPB) {
        __syncthreads();
        uint32_t idx = c0 + threadIdx.x;
        ch[threadIdx.x] = (idx < n) ? cb[idx] : 0ull;   // dummy 0 never counts
        __syncthreads();
        #pragma unroll 8
        for (uint32_t k = 0; k < RANK_TPB; ++k) rank += (ch[k] > my) ? 1u : 0u;
    }
    if (myIdx >= n || rank >= PRE_NMS) return;
    unsigned long long p = my;
    uint32_t key = (uint32_t)(p >> 32);
    uint32_t i = ~(uint32_t)p;
    uint32_t u = (key & 0x80000000u) ? (key ^ 0x80000000u) : ~key;
    float v = __uint_as_float(u);
    scores[b * PRE_NMS + rank] = 1.0f / (1.0f + expf(-v));
    int a = (int)(i & 1);
    int loc = (int)(i >> 1);
    int tt = b * LOCS + loc;
    float d[7];
    #pragma unroll
    for (int c = 0; c < 7; ++c) d[c] = breg[(size_t)(a * 7 + c) * HT + tt];
    const float* anc = anchors + ((size_t)b * NPB + i) * 7;
    float xa = anc[0], ya = anc[1], za = anc[2];
    float wa = anc[3], la = anc[4], ha = anc[5], ra = anc[6];
    float diag = sqrtf(wa * wa + la * la);
    float X = d[0] * diag + xa;
    float Y = d[1] * diag + ya;
    float Z = d[2] * ha + za;
    float W = expf(d[3]) * wa;
    float L = expf(d[4]) * la;
    float H = expf(d[5]) * ha;
    float R = d[6] + ra;
    float* bx = boxes + ((size_t)b * PRE_NMS + rank) * 7;
    bx[0] = X; bx[1] = Y; bx[2] = Z; bx[3] = W; bx[4] = L; bx[5] = H; bx[6] = R;
    float4* ep = (float4*)(ext + ((size_t)b * PRE_NMS + rank) * 8);
    ep[0] = make_float4(X - 0.5f * W, X + 0.5f * W, Y - 0.5f * L, Y + 0.5f * L);
    ep[1] = make_float4(Z, Z + H, fmaxf(W, 0.f) * fmaxf(L, 0.f) * fmaxf(H, 0.f), 0.f);
}

// ---------------- K5: suppressing pairs, 64x64 tile grid ----------------
__global__ __launch_bounds__(64) void k_pairs(const float* __restrict__ ext,
                                              uint32_t* __restrict__ pairCount,
                                              unsigned long long* __restrict__ pairs) {
    int b = blockIdx.x / (NT * NT);
    int r = blockIdx.x % (NT * NT);
    int ti = r / NT, tj = r % NT;
    if (tj < ti) return;
    __shared__ float bi[PTILE][8];
    const float* eb = ext + (size_t)b * PRE_NMS * 8;
    {   // stage i-tile extents: 128 float4s, coalesced
        const float4* src = (const float4*)(eb + (size_t)ti * PTILE * 8);
        float4* dst = (float4*)&bi[0][0];
        dst[threadIdx.x] = src[threadIdx.x];
        dst[threadIdx.x + 64] = src[threadIdx.x + 64];
    }
    __syncthreads();
    int j = tj * PTILE + threadIdx.x;
    const float4* jp = (const float4*)(eb + (size_t)j * 8);
    float4 j0 = jp[0], j1 = jp[1];
    float xj1 = j0.x, xj2 = j0.y, yj1 = j0.z, yj2 = j0.w;
    float zj1 = j1.x, zj2 = j1.y, vj = j1.z;
    int iimax = (ti == tj) ? (int)threadIdx.x : PTILE;   // enforce i < j
    for (int ii = 0; ii < iimax; ++ii) {
        float ix = fminf(bi[ii][1], xj2) - fmaxf(bi[ii][0], xj1); if (ix <= 0.f) continue;
        float iy = fminf(bi[ii][3], yj2) - fmaxf(bi[ii][2], yj1); if (iy <= 0.f) continue;
        float iz = fminf(bi[ii][5], zj2) - fmaxf(bi[ii][4], zj1); if (iz <= 0.f) continue;
        float inter = ix * iy * iz;
        float iou = inter / (bi[ii][6] + vj - inter + 1e-8f);
        if (iou > NMS_THRESH_F) {
            uint32_t pos = atomicAdd(&pairCount[b], 1u);
            if (pos < PAIR_CAP)
                pairs[(size_t)b * PAIR_CAP + pos] =
                    ((unsigned long long)(uint32_t)(ti * PTILE + ii) << 32) | (uint32_t)j;
        }
    }
}

// ---------------- K6: serial greedy scan over tiny pair list + emit output ----------------
__global__ __launch_bounds__(256) void k_scan_out(const float* __restrict__ boxes,
                                                  const float* __restrict__ scores,
                                                  const uint32_t* __restrict__ ctrl,
                                                  const unsigned long long* __restrict__ pairs,
                                                  float* __restrict__ out) {
    int b = blockIdx.x;
    __shared__ unsigned long long pl[PAIR_CAP];
    __shared__ unsigned long long keep[32];
    __shared__ uint32_t keptPre[33];
    uint32_t np = ctrl[12 + b];
    if (np > PAIR_CAP) np = PAIR_CAP;
    unsigned np2 = 64;
    while (np2 < np) np2 <<= 1;
    for (unsigned j = threadIdx.x; j < np2; j += 256)
        pl[j] = (j < np) ? pairs[(size_t)b * PAIR_CAP + j] : ~0ull;
    __syncthreads();
    for (unsigned size = 2; size <= np2; size <<= 1)
        for (unsigned stride = size >> 1; stride > 0; stride >>= 1) {
            for (unsigned q = threadIdx.x; q < (np2 >> 1); q += 256) {
                unsigned p = 2 * q - (q & (stride - 1));
                unsigned partner = p + stride;
                bool up = ((p & size) == 0);
                unsigned long long x = pl[p], y = pl[partner];
                if (up ? (x > y) : (x < y)) { pl[p] = y; pl[partner] = x; }  // ascending
            }
            __syncthreads();
        }
    if (threadIdx.x == 0) {
        for (int w = 0; w < 32; ++w) keep[w] = ~0ull;
        for (unsigned p = 0; p < np; ++p) {
            unsigned long long e = pl[p];
            uint32_t i = (uint32_t)(e >> 32), j = (uint32_t)e;
            if ((keep[i >> 6] >> (i & 63)) & 1ull)
                keep[j >> 6] &= ~(1ull << (j & 63));
        }
        uint32_t acc = 0;
        for (int w = 0; w < 32; ++w) { keptPre[w] = acc; acc += (uint32_t)__popcll(keep[w]); }
        keptPre[32] = acc;
    }
    __syncthreads();
    uint32_t totalKept = keptPre[32];
    for (int i = threadIdx.x; i < PRE_NMS; i += 256) {
        int w = i >> 6, bit = i & 63;
        unsigned long long kw = keep[w];
        uint32_t keptBefore = keptPre[w] + (uint32_t)__popcll(kw & ((1ull << bit) - 1ull));
        bool isKept = (kw >> bit) & 1ull;
        uint32_t pos = isKept ? keptBefore : (totalKept + (uint32_t)i - keptBefore);
        if (pos < POST_NMS) {
            float* o = out + ((size_t)b * POST_NMS + pos) * 8;
            const float* bx = boxes + ((size_t)b * PRE_NMS + i) * 7;
            #pragma unroll
            for (int c = 0; c < 7; ++c) o[c] = bx[c];
            o[7] = isKept ? scores[b * PRE_NMS + i] : 0.0f;
        }
    }
}

extern "C" void kernel_launch(void* const* d_in, const int* in_sizes, int n_in,
                              void* d_out, int out_size, void* d_ws, size_t ws_size,
                              hipStream_t stream) {
    const float* obj = (const float*)d_in[0];
    const float* breg = (const float*)d_in[1];
    const float* anchors = (const float*)d_in[2];
    float* out = (float*)d_out;
    char* ws = (char*)d_ws;
    uint32_t* hist = (uint32_t*)(ws + OFF_HIST);
    uint32_t* ctrl = (uint32_t*)(ws + OFF_CTRL);
    unsigned long long* cand = (unsigned long long*)(ws + OFF_CAND);
    float* boxes = (float*)(ws + OFF_BOXES);
    float* scores = (float*)(ws + OFF_SCORE);
    unsigned long long* pairs = (unsigned long long*)(ws + OFF_PAIRS);
    float* ext = (float*)(ws + OFF_EXT);

    hipMemsetAsync(d_ws, 0, OFF_CAND, stream);  // zero hist + ctrl each call

    k_hist<<<TOTAL / 4096, 256, 0, stream>>>((const float4*)obj, hist);
    k_thresh<<<BATCH, 64, 0, stream>>>(hist, ctrl);
    k_compact<<<TOTAL / 4096, 256, 0, stream>>>((const float4*)obj, ctrl, cand);
    k_rank<<<BATCH * RANK_BPB, RANK_TPB, 0, stream>>>(breg, anchors, ctrl, cand, boxes, scores, ext);
    k_pairs<<<BATCH * NT * NT, 64, 0, stream>>>(ext, ctrl + 12, pairs);
    k_scan_out<<<BATCH, 256, 0, stream>>>(boxes, scores, ctrl, pairs, out);
}

// Round 6
// 71.903 us; speedup vs baseline: 6.9447x; 1.5415x over previous
//
#include <hip/hip_runtime.h>
#include <stdint.h>

#define BATCH 4
#define A_NUM 2
#define LOCS 262144                 // HT / B
#define HT (BATCH * LOCS)           // 1048576
#define NPB (LOCS * A_NUM)          // 524288 candidates per batch
#define TOTAL (A_NUM * HT)          // 2097152 objectness elements
#define PRE_NMS 2048
#define POST_NMS 512
#define NMS_THRESH_F 0.7f
#define NBUCKET 4096
#define NCOPY 8                     // hist copies per batch (atomic contention /8)
#define CAND_CAP 8192
#define PAIR_CAP 4096
#define PTILE 64
#define NT (PRE_NMS / PTILE)        // 32
#define RANK_TPB 128
#define RANK_BPB (CAND_CAP / RANK_TPB)   // 64 cand-blocks per batch
#define NSLICE 16

// workspace byte offsets
#define OFF_HIST 0                  // 4 * 8 * 4096 * 4 = 524288
#define OFF_CTRL 524288             // 512: [0..3]=candCount [4..7]=T [8..11]=countAbove [12..15]=pairCount
#define OFF_RANK 524800             // 4 * 8192 * 4 = 131072 (zeroed by memset)
#define OFF_CAND 655872             // 4 * 8192 * 8   = 262144
#define OFF_BOXES 918016            // 4 * 2048 * 7*4 = 229376
#define OFF_SCORE 1147392           // 4 * 2048 * 4   = 32768
#define OFF_PAIRS 1180160           // 4 * 4096 * 8   = 131072
#define OFF_EXT 1311232             // 4 * 2048 * 8*4 = 262144
// total ws use: 1573376 bytes

__device__ __forceinline__ uint32_t f2key(float f) {
    uint32_t u = __float_as_uint(f);
    return (u & 0x80000000u) ? ~u : (u | 0x80000000u);  // monotone ascending
}

// ---------------- K1: per-batch histogram over top-12 key bits ----------------
__global__ __launch_bounds__(256) void k_hist(const float4* __restrict__ obj4,
                                              uint32_t* __restrict__ hist) {
    __shared__ uint32_t h[NBUCKET];
    for (int j = threadIdx.x; j < NBUCKET; j += 256) h[j] = 0;
    __syncthreads();
    int base4 = blockIdx.x * 1024;               // float4 units
    int b = ((base4 * 4) % HT) / LOCS;
    for (int k = 0; k < 4; ++k) {
        float4 v = obj4[base4 + k * 256 + threadIdx.x];
        atomicAdd(&h[f2key(v.x) >> 20], 1u);
        atomicAdd(&h[f2key(v.y) >> 20], 1u);
        atomicAdd(&h[f2key(v.z) >> 20], 1u);
        atomicAdd(&h[f2key(v.w) >> 20], 1u);
    }
    __syncthreads();
    uint32_t* gh = hist + ((size_t)b * NCOPY + (blockIdx.x & (NCOPY - 1))) * NBUCKET;
    for (int j = threadIdx.x; j < NBUCKET; j += 256)
        if (h[j]) atomicAdd(&gh[j], h[j]);
}

// ---------------- K2: find threshold bucket T and countAbove ----------------
__global__ __launch_bounds__(64) void k_thresh(const uint32_t* __restrict__ hist,
                                               uint32_t* __restrict__ ctrl) {
    int b = blockIdx.x;
    const uint32_t* gh = hist + (size_t)b * NCOPY * NBUCKET;
    __shared__ uint32_t bs[NBUCKET];
    __shared__ uint32_t s[64], sa[64];
    int l = threadIdx.x;                          // 64 threads
    uint32_t sum = 0;
    for (int j = 0; j < 64; ++j) {
        uint32_t v = 0;
        #pragma unroll
        for (int c = 0; c < NCOPY; ++c) v += gh[(size_t)c * NBUCKET + l * 64 + j];
        bs[l * 64 + j] = v;
        sum += v;
    }
    s[l] = sum;
    __syncthreads();
    if (l == 0) {
        uint32_t acc = 0;
        for (int m = 63; m >= 0; --m) { sa[m] = acc; acc += s[m]; }
    }
    __syncthreads();
    if (sa[l] < PRE_NMS && sa[l] + s[l] >= PRE_NMS) {   // unique lane
        uint32_t cum = sa[l];
        for (int j = 63; j >= 0; --j) {
            uint32_t hv = bs[l * 64 + j];
            if (cum + hv >= PRE_NMS) { ctrl[4 + b] = (uint32_t)(l * 64 + j); ctrl[8 + b] = cum; break; }
            cum += hv;
        }
    }
}

// ---------------- K3: compact candidates with bucket >= T (block-staged) ----------------
__global__ __launch_bounds__(256) void k_compact(const float4* __restrict__ obj4,
                                                 uint32_t* __restrict__ ctrl,
                                                 unsigned long long* __restrict__ cand) {
    __shared__ uint32_t cnt, basepos;
    __shared__ unsigned long long buf[4096];      // block covers 4096 elems -> no overflow
    if (threadIdx.x == 0) cnt = 0;
    __syncthreads();
    int base4 = blockIdx.x * 1024;
    int belem = base4 * 4;
    int b = (belem % HT) / LOCS;
    int a = belem / HT;
    uint32_t T = ctrl[4 + b];
    for (int k = 0; k < 4; ++k) {
        int g4 = base4 + k * 256 + threadIdx.x;
        float4 v = obj4[g4];
        float vals[4] = {v.x, v.y, v.z, v.w};
        #pragma unroll
        for (int c = 0; c < 4; ++c) {
            uint32_t key = f2key(vals[c]);
            if ((key >> 20) >= T) {
                int g = g4 * 4 + c;
                int loc = g & (LOCS - 1);         // LOCS is pow2
                uint32_t i = (uint32_t)(loc * A_NUM + a);
                uint32_t pos = atomicAdd(&cnt, 1u);   // LDS atomic
                buf[pos] = ((unsigned long long)key << 32) | (uint32_t)(~i);
            }
        }
    }
    __syncthreads();
    if (threadIdx.x == 0) basepos = atomicAdd(&ctrl[b], cnt);  // one global atomic/block
    __syncthreads();
    uint32_t n = cnt, bp = basepos;
    for (uint32_t j = threadIdx.x; j < n; j += 256) {
        uint32_t p = bp + j;
        if (p < CAND_CAP) cand[(size_t)b * CAND_CAP + p] = buf[j];
    }
}

// ---------------- K4a: partial rank over compare-slices ----------------
// grid: BATCH * RANK_BPB * NSLICE blocks x 128 thr. Block (b,t,s): candidates
// t*128.. vs chunks c == s (mod NSLICE); atomicAdd partial rank.
__global__ __launch_bounds__(RANK_TPB) void k_rank_partial(
    const uint32_t* __restrict__ ctrl, const unsigned long long* __restrict__ cand,
    uint32_t* __restrict__ rankbuf) {
    int rem = blockIdx.x;
    int s = rem % NSLICE; rem /= NSLICE;
    int t = rem % RANK_BPB;
    int b = rem / RANK_BPB;
    uint32_t n = ctrl[b];
    if (n > CAND_CAP) n = CAND_CAP;
    if ((uint32_t)(t * RANK_TPB) >= n) return;
    __shared__ __align__(16) unsigned long long ch[RANK_TPB];
    const unsigned long long* cb = cand + (size_t)b * CAND_CAP;
    uint32_t myIdx = t * RANK_TPB + threadIdx.x;
    unsigned long long my = (myIdx < n) ? cb[myIdx] : ~0ull;
    uint32_t rank = 0;
    for (uint32_t c = (uint32_t)s; c * RANK_TPB < n; c += NSLICE) {
        uint32_t c0 = c * RANK_TPB;
        __syncthreads();
        uint32_t idx = c0 + threadIdx.x;
        ch[threadIdx.x] = (idx < n) ? cb[idx] : 0ull;   // dummy 0 never counts
        __syncthreads();
        #pragma unroll 16
        for (uint32_t k = 0; k < RANK_TPB; k += 2) {
            ulonglong2 cv = *(const ulonglong2*)&ch[k];
            rank += (cv.x > my) ? 1u : 0u;
            rank += (cv.y > my) ? 1u : 0u;
        }
    }
    if (myIdx < n && rank)
        atomicAdd(&rankbuf[(size_t)b * CAND_CAP + myIdx], rank);
}

// ---------------- K4b: decode candidate at its final rank ----------------
__global__ __launch_bounds__(RANK_TPB) void k_decode(
    const float* __restrict__ breg, const float* __restrict__ anchors,
    const uint32_t* __restrict__ ctrl, const unsigned long long* __restrict__ cand,
    const uint32_t* __restrict__ rankbuf,
    float* __restrict__ boxes, float* __restrict__ scores, float* __restrict__ ext) {
    int b = blockIdx.x / RANK_BPB;
    int t = blockIdx.x % RANK_BPB;
    uint32_t n = ctrl[b];
    if (n > CAND_CAP) n = CAND_CAP;
    uint32_t myIdx = t * RANK_TPB + threadIdx.x;
    if (myIdx >= n) return;
    uint32_t rank = rankbuf[(size_t)b * CAND_CAP + myIdx];
    if (rank >= PRE_NMS) return;
    unsigned long long p = cand[(size_t)b * CAND_CAP + myIdx];
    uint32_t key = (uint32_t)(p >> 32);
    uint32_t i = ~(uint32_t)p;
    uint32_t u = (key & 0x80000000u) ? (key ^ 0x80000000u) : ~key;
    float v = __uint_as_float(u);
    scores[b * PRE_NMS + rank] = 1.0f / (1.0f + expf(-v));
    int a = (int)(i & 1);
    int loc = (int)(i >> 1);
    int tt = b * LOCS + loc;
    float d[7];
    #pragma unroll
    for (int c = 0; c < 7; ++c) d[c] = breg[(size_t)(a * 7 + c) * HT + tt];
    const float* anc = anchors + ((size_t)b * NPB + i) * 7;
    float xa = anc[0], ya = anc[1], za = anc[2];
    float wa = anc[3], la = anc[4], ha = anc[5], ra = anc[6];
    float diag = sqrtf(wa * wa + la * la);
    float X = d[0] * diag + xa;
    float Y = d[1] * diag + ya;
    float Z = d[2] * ha + za;
    float W = expf(d[3]) * wa;
    float L = expf(d[4]) * la;
    float H = expf(d[5]) * ha;
    float R = d[6] + ra;
    float* bx = boxes + ((size_t)b * PRE_NMS + rank) * 7;
    bx[0] = X; bx[1] = Y; bx[2] = Z; bx[3] = W; bx[4] = L; bx[5] = H; bx[6] = R;
    float4* ep = (float4*)(ext + ((size_t)b * PRE_NMS + rank) * 8);
    ep[0] = make_float4(X - 0.5f * W, X + 0.5f * W, Y - 0.5f * L, Y + 0.5f * L);
    ep[1] = make_float4(Z, Z + H, fmaxf(W, 0.f) * fmaxf(L, 0.f) * fmaxf(H, 0.f), 0.f);
}

// ---------------- K5: suppressing pairs, 64x64 tile grid ----------------
__global__ __launch_bounds__(64) void k_pairs(const float* __restrict__ ext,
                                              uint32_t* __restrict__ pairCount,
                                              unsigned long long* __restrict__ pairs) {
    int b = blockIdx.x / (NT * NT);
    int r = blockIdx.x % (NT * NT);
    int ti = r / NT, tj = r % NT;
    if (tj < ti) return;
    __shared__ float bi[PTILE][8];
    const float* eb = ext + (size_t)b * PRE_NMS * 8;
    {   // stage i-tile extents: 128 float4s, coalesced
        const float4* src = (const float4*)(eb + (size_t)ti * PTILE * 8);
        float4* dst = (float4*)&bi[0][0];
        dst[threadIdx.x] = src[threadIdx.x];
        dst[threadIdx.x + 64] = src[threadIdx.x + 64];
    }
    __syncthreads();
    int j = tj * PTILE + threadIdx.x;
    const float4* jp = (const float4*)(eb + (size_t)j * 8);
    float4 j0 = jp[0], j1 = jp[1];
    float xj1 = j0.x, xj2 = j0.y, yj1 = j0.z, yj2 = j0.w;
    float zj1 = j1.x, zj2 = j1.y, vj = j1.z;
    int iimax = (ti == tj) ? (int)threadIdx.x : PTILE;   // enforce i < j
    for (int ii = 0; ii < iimax; ++ii) {
        float ix = fminf(bi[ii][1], xj2) - fmaxf(bi[ii][0], xj1); if (ix <= 0.f) continue;
        float iy = fminf(bi[ii][3], yj2) - fmaxf(bi[ii][2], yj1); if (iy <= 0.f) continue;
        float iz = fminf(bi[ii][5], zj2) - fmaxf(bi[ii][4], zj1); if (iz <= 0.f) continue;
        float inter = ix * iy * iz;
        float iou = inter / (bi[ii][6] + vj - inter + 1e-8f);
        if (iou > NMS_THRESH_F) {
            uint32_t pos = atomicAdd(&pairCount[b], 1u);
            if (pos < PAIR_CAP)
                pairs[(size_t)b * PAIR_CAP + pos] =
                    ((unsigned long long)(uint32_t)(ti * PTILE + ii) << 32) | (uint32_t)j;
        }
    }
}

// ---------------- K6: serial greedy scan over tiny pair list + emit output ----------------
__global__ __launch_bounds__(256) void k_scan_out(const float* __restrict__ boxes,
                                                  const float* __restrict__ scores,
                                                  const uint32_t* __restrict__ ctrl,
                                                  const unsigned long long* __restrict__ pairs,
                                                  float* __restrict__ out) {
    int b = blockIdx.x;
    __shared__ unsigned long long pl[PAIR_CAP];
    __shared__ unsigned long long keep[32];
    __shared__ uint32_t keptPre[33];
    uint32_t np = ctrl[12 + b];
    if (np > PAIR_CAP) np = PAIR_CAP;
    unsigned np2 = 64;
    while (np2 < np) np2 <<= 1;
    for (unsigned j = threadIdx.x; j < np2; j += 256)
        pl[j] = (j < np) ? pairs[(size_t)b * PAIR_CAP + j] : ~0ull;
    __syncthreads();
    for (unsigned size = 2; size <= np2; size <<= 1)
        for (unsigned stride = size >> 1; stride > 0; stride >>= 1) {
            for (unsigned q = threadIdx.x; q < (np2 >> 1); q += 256) {
                unsigned p = 2 * q - (q & (stride - 1));
                unsigned partner = p + stride;
                bool up = ((p & size) == 0);
                unsigned long long x = pl[p], y = pl[partner];
                if (up ? (x > y) : (x < y)) { pl[p] = y; pl[partner] = x; }  // ascending
            }
            __syncthreads();
        }
    if (threadIdx.x == 0) {
        for (int w = 0; w < 32; ++w) keep[w] = ~0ull;
        for (unsigned p = 0; p < np; ++p) {
            unsigned long long e = pl[p];
            uint32_t i = (uint32_t)(e >> 32), j = (uint32_t)e;
            if ((keep[i >> 6] >> (i & 63)) & 1ull)
                keep[j >> 6] &= ~(1ull << (j & 63));
        }
        uint32_t acc = 0;
        for (int w = 0; w < 32; ++w) { keptPre[w] = acc; acc += (uint32_t)__popcll(keep[w]); }
        keptPre[32] = acc;
    }
    __syncthreads();
    uint32_t totalKept = keptPre[32];
    for (int i = threadIdx.x; i < PRE_NMS; i += 256) {
        int w = i >> 6, bit = i & 63;
        unsigned long long kw = keep[w];
        uint32_t keptBefore = keptPre[w] + (uint32_t)__popcll(kw & ((1ull << bit) - 1ull));
        bool isKept = (kw >> bit) & 1ull;
        uint32_t pos = isKept ? keptBefore : (totalKept + (uint32_t)i - keptBefore);
        if (pos < POST_NMS) {
            float* o = out + ((size_t)b * POST_NMS + pos) * 8;
            const float* bx = boxes + ((size_t)b * PRE_NMS + i) * 7;
            #pragma unroll
            for (int c = 0; c < 7; ++c) o[c] = bx[c];
            o[7] = isKept ? scores[b * PRE_NMS + i] : 0.0f;
        }
    }
}

extern "C" void kernel_launch(void* const* d_in, const int* in_sizes, int n_in,
                              void* d_out, int out_size, void* d_ws, size_t ws_size,
                              hipStream_t stream) {
    const float* obj = (const float*)d_in[0];
    const float* breg = (const float*)d_in[1];
    const float* anchors = (const float*)d_in[2];
    float* out = (float*)d_out;
    char* ws = (char*)d_ws;
    uint32_t* hist = (uint32_t*)(ws + OFF_HIST);
    uint32_t* ctrl = (uint32_t*)(ws + OFF_CTRL);
    uint32_t* rankbuf = (uint32_t*)(ws + OFF_RANK);
    unsigned long long* cand = (unsigned long long*)(ws + OFF_CAND);
    float* boxes = (float*)(ws + OFF_BOXES);
    float* scores = (float*)(ws + OFF_SCORE);
    unsigned long long* pairs = (unsigned long long*)(ws + OFF_PAIRS);
    float* ext = (float*)(ws + OFF_EXT);

    hipMemsetAsync(d_ws, 0, OFF_CAND, stream);  // zero hist + ctrl + rankbuf each call

    k_hist<<<TOTAL / 4096, 256, 0, stream>>>((const float4*)obj, hist);
    k_thresh<<<BATCH, 64, 0, stream>>>(hist, ctrl);
    k_compact<<<TOTAL / 4096, 256, 0, stream>>>((const float4*)obj, ctrl, cand);
    k_rank_partial<<<BATCH * RANK_BPB * NSLICE, RANK_TPB, 0, stream>>>(ctrl, cand, rankbuf);
    k_decode<<<BATCH * RANK_BPB, RANK_TPB, 0, stream>>>(breg, anchors, ctrl, cand, rankbuf,
                                                        boxes, scores, ext);
    k_pairs<<<BATCH * NT * NT, 64, 0, stream>>>(ext, ctrl + 12, pairs);
    k_scan_out<<<BATCH, 256, 0, stream>>>(boxes, scores, ctrl, pairs, out);
}